// Round 7
// baseline (1165.452 us; speedup 1.0000x reference)
//
#include <hip/hip_runtime.h>

#define N_NODES 100000
#define N_EDGES 1600000
#define IN_F 128
#define H_F 64
#define C_F 16

#define BIN_SH 7
#define BIN_NODES 128          // 1 << BIN_SH
#define NBINS 782              // ceil(100000 / 128) == grid size
#define BCAP 2816              // fixed bin capacity (mean 2048, sigma 45 -> +17s)
#define PARTB 391              // partition blocks (4096 edges each, R2-proven)
#define NTILES 6250            // 16-node row tiles for gemm1
#define RMAXC 6                // ceil(BCAP / 512) records/thread in sort cache
#define AGG_STRIDE 36          // LDS agg tile row stride in words (144 B)

typedef __attribute__((ext_vector_type(8))) short bf16x8;  // 8 bf16 (4 VGPRs)
typedef __attribute__((ext_vector_type(4))) float f32x4;   // MFMA C/D

// fp32 -> bf16 round-to-nearest-even (finite inputs)
__device__ inline unsigned short f2bf(float f) {
  unsigned u = __float_as_uint(f);
  unsigned r = (u + 0x7fff + ((u >> 16) & 1)) >> 16;
  return (unsigned short)r;
}

// Persistent-grid barrier. Co-residency guaranteed: LDS 34.9KB -> 4 blk/CU,
// launch_bounds(512,8) caps VGPR at 64, grid 782 <= 1024 slots.
// KEY FIX vs R6: spin uses RELAXED loads (no per-poll buffer_inv; the R6
// ACQUIRE spin caused a chip-wide L2-invalidation storm, 982us). Release =
// leader's RELEASE fetch_add (wbl2 flushes this XCD's L2 incl. all waves'
// stores, drained by the preceding syncthreads). Acquire = one post-barrier
// threadfence per wave. This fencing arrangement passed correctness in R6.
__device__ inline void gridbar(int* c) {
  __threadfence();
  __syncthreads();
  if (threadIdx.x == 0) {
    __hip_atomic_fetch_add(c, 1, __ATOMIC_RELEASE, __HIP_MEMORY_SCOPE_AGENT);
    while (__hip_atomic_load(c, __ATOMIC_RELAXED, __HIP_MEMORY_SCOPE_AGENT) <
           NBINS) {
      __builtin_amdgcn_s_sleep(16);
    }
  }
  __syncthreads();
  __threadfence();  // acquire: invalidate stale lines once
}

// One 16-node GEMM1 row tile: H1b[rt*16..+16) = bf16(X @ W1) (R2-proven body)
__device__ inline void gemm1_tile(int rt, int lane, const short* ldsB,
                                  const float* __restrict__ X,
                                  unsigned short* __restrict__ H1b) {
  int node0 = rt * 16;
  int l = lane & 15, q = lane >> 4;
  const float* xp = X + (size_t)(node0 + l) * IN_F + q * 8;
  f32x4 acc[4] = {f32x4{0.f, 0.f, 0.f, 0.f}, f32x4{0.f, 0.f, 0.f, 0.f},
                  f32x4{0.f, 0.f, 0.f, 0.f}, f32x4{0.f, 0.f, 0.f, 0.f}};
#pragma unroll
  for (int s = 0; s < 4; ++s) {
    float4 x0 = *(const float4*)(xp + s * 32);
    float4 x1 = *(const float4*)(xp + s * 32 + 4);
    bf16x8 a;
    a[0] = f2bf(x0.x); a[1] = f2bf(x0.y); a[2] = f2bf(x0.z); a[3] = f2bf(x0.w);
    a[4] = f2bf(x1.x); a[5] = f2bf(x1.y); a[6] = f2bf(x1.z); a[7] = f2bf(x1.w);
#pragma unroll
    for (int c = 0; c < 4; ++c) {
      bf16x8 bb = *(const bf16x8*)&ldsB[(c * 4 + s) * 512 + lane * 8];
      acc[c] = __builtin_amdgcn_mfma_f32_16x16x32_bf16(a, bb, acc[c], 0, 0, 0);
    }
  }
  // C/D: col = lane&15 (feat), row = q*4 + reg (node)
#pragma unroll
  for (int c = 0; c < 4; ++c)
#pragma unroll
    for (int r = 0; r < 4; ++r)
      H1b[(size_t)(node0 + q * 4 + r) * H_F + c * 16 + l] = f2bf(acc[c][r]);
}

// ---------------- single persistent mega-kernel (512 thr = R2 geometry) ---
// Phase A: gemm1 (all blocks; part blocks 4 tiles on waves 0-3, gemm blocks
//          12 tiles) || partition edge-load + LDS hist (b<PARTB).
// Phase B: reserve (global atomics) + scatter records to ebin (b<PARTB).
// Phase C: per-bin counting sort (ebin -> LDS srt) + gather1 (8 waves x 16
//          nodes, R2 body) + bias/relu + fused gemm2 -> H2b.
// Phase D: gather2 straight from LDS-resident srt -> out (R2 body).
__global__ __launch_bounds__(512, 8) void gcn_mega(
    const int* __restrict__ src, const int* __restrict__ dst,
    const float* __restrict__ ew, const float* __restrict__ X,
    const float* __restrict__ W1, const float* __restrict__ b1,
    const float* __restrict__ W2, const float* __restrict__ b2,
    int* __restrict__ binCnt, int2* __restrict__ ebin,
    unsigned short* __restrict__ H1b, unsigned short* __restrict__ H2b,
    float* __restrict__ out, int* __restrict__ bar) {
  // LDS union (34928 B total -> 4 blocks/CU; grid 782 needs 3.06/CU):
  //   A/B: ldsB[0..16384) | hist[16384..19512) | base[19512..22640)
  //   C  : aggU[0..18432) | ldsW2[18432..20480) | cur[20480..20992)
  //   C,D: srt[22640..33904) | h[33904..34416) | sc[34416..34928)
  __shared__ __align__(16) char L[34928];
  short* ldsB = (short*)L;
  int* hist = (int*)(L + 16384);
  int* base = (int*)(L + 19512);
  unsigned* aggU = (unsigned*)L;
  short* ldsW2 = (short*)(L + 18432);
  int* cur = (int*)(L + 20480);
  unsigned* srt = (unsigned*)(L + 22640);
  int* h = (int*)(L + 33904);
  int* sc = (int*)(L + 34416);

  int b = blockIdx.x, tid = threadIdx.x;
  int wave = tid >> 6, lane = tid & 63;

  unsigned key[8], aux[8];  // partition records (live A -> B, b<PARTB only)

  // ======================= Phase A =======================
  if (b < PARTB) {
    for (int i = tid; i < NBINS; i += 512) hist[i] = 0;
  }
  // W1 fragment fill (all blocks)
  for (int idx = tid; idx < 16 * 512; idx += 512) {
    int frag = idx >> 9;    // c*4 + s
    int entry = idx & 511;  // lane*8 + j
    int ln = entry >> 3, j = entry & 7;
    int c = frag >> 2, s = frag & 3;
    int k = s * 32 + (ln >> 4) * 8 + j;
    int n = c * 16 + (ln & 15);
    ldsB[idx] = (short)f2bf(W1[k * H_F + n]);
  }
  __syncthreads();
  // gemm1: part blocks 4 tiles (waves 0-3), gemm blocks 12 tiles (1.5 reps)
  if (b < PARTB) {
    if (wave < 4) gemm1_tile(b * 4 + wave, lane, ldsB, X, H1b);  // [0,1564)
  } else {
#pragma unroll
    for (int rep = 0; rep < 2; ++rep) {
      int r = rep * 8 + wave;
      if (r < 12) {
        int rt = 1564 + (b - PARTB) * 12 + r;
        if (rt < NTILES) gemm1_tile(rt, lane, ldsB, X, H1b);
      }
    }
  }
  // partition: load 4096 edges (8/thread) to regs + LDS hist
  if (b < PARTB) {
    int i0 = b * 1024;  // int4 index base
    int iHi = i0 + 1024;
    if (iHi > N_EDGES / 4) iHi = N_EDGES / 4;
    const int4* d4p = (const int4*)dst;
    const int4* s4p = (const int4*)src;
    const float4* w4p = (const float4*)ew;
#pragma unroll
    for (int it = 0; it < 2; ++it) {
      int i = i0 + it * 512 + tid;
      if (i < iHi) {
        int4 d = d4p[i];
        int4 s = s4p[i];
        float4 w = w4p[i];
#pragma unroll
        for (int j = 0; j < 4; ++j) {
          int dd = (&d.x)[j];
          int ss = (&s.x)[j];
          float ww = (&w.x)[j];
          int bb = dd >> BIN_SH;
          unsigned wf = (unsigned)(ww * 32767.0f + 0.5f);
          key[it * 4 + j] =
              (unsigned)ss | ((unsigned)(dd & (BIN_NODES - 1)) << 17);
          aux[it * 4 + j] = wf | ((unsigned)bb << 15);
          atomicAdd(&hist[bb], 1);
        }
      }
    }
  }
  gridbar(&bar[0]);

  // ======================= Phase B =======================
  if (b < PARTB) {
    for (int t = tid; t < NBINS; t += 512)
      base[t] = hist[t] ? atomicAdd(&binCnt[t], hist[t]) : 0;
    __syncthreads();
    int i0 = b * 1024;
    int iHi = i0 + 1024;
    if (iHi > N_EDGES / 4) iHi = N_EDGES / 4;
#pragma unroll
    for (int it = 0; it < 2; ++it) {
      int i = i0 + it * 512 + tid;
      if (i < iHi) {
        int pos[4];
#pragma unroll
        for (int j = 0; j < 4; ++j)
          pos[j] = atomicAdd(&base[aux[it * 4 + j] >> 15], 1);
#pragma unroll
        for (int j = 0; j < 4; ++j)
          ebin[(size_t)(aux[it * 4 + j] >> 15) * BCAP + pos[j]] =
              make_int2((int)key[it * 4 + j], (int)(aux[it * 4 + j] & 0x7FFF));
      }
    }
  }
  gridbar(&bar[1]);

  // ======================= Phase C =======================
  {
    // W2 swizzle fill
    for (int idx = tid; idx < 1024; idx += 512) {
      int sfrag = idx >> 9;
      int entry = idx & 511;
      int ln = entry >> 3, j = entry & 7;
      int k = sfrag * 32 + (ln >> 4) * 8 + j;
      int c = ln & 15;
      ldsW2[idx] = (short)f2bf(W2[k * C_F + c]);
    }
    if (tid < BIN_NODES) h[tid] = 0;
    __syncthreads();
    int lo = b * BCAP;
    int cnt = binCnt[b];
    unsigned rk[RMAXC];
    int rd[RMAXC];
    int rn = 0;
#pragma unroll
    for (int j = 0; j < RMAXC; ++j) {
      int e = j * 512 + tid;
      if (e < cnt) {
        int2 r = ebin[lo + e];
        int dl = (((unsigned)r.x) >> 17) & (BIN_NODES - 1);
        rk[j] = ((unsigned)r.x & 0x1FFFF) | ((unsigned)r.y << 17);
        rd[j] = dl;
        atomicAdd(&h[dl], 1);
        rn = j + 1;
      }
    }
    __syncthreads();
    if (tid < BIN_NODES) sc[tid] = h[tid];
    __syncthreads();
#pragma unroll
    for (int d = 1; d < BIN_NODES; d <<= 1) {
      int t = 0;
      if (tid < BIN_NODES && tid >= d) t = sc[tid - d];
      __syncthreads();
      if (tid < BIN_NODES) sc[tid] += t;
      __syncthreads();
    }
    if (tid < BIN_NODES) cur[tid] = sc[tid] - h[tid];
    __syncthreads();
#pragma unroll
    for (int j = 0; j < RMAXC; ++j)
      if (j < rn) {
        int pos = atomicAdd(&cur[rd[j]], 1);
        srt[pos] = rk[j];
      }
    __syncthreads();
    // ---- gather1: 8 waves x 16 nodes (R2 body) ----
    const uint2* H1q = (const uint2*)H1b;
    int g = lane >> 4, li = lane & 15;
    const float wsc = 1.0f / 32767.0f;
    float bb0 = b1[li * 4], bb1 = b1[li * 4 + 1];
    float bb2 = b1[li * 4 + 2], bb3 = b1[li * 4 + 3];
    for (int k = 0; k < 16; ++k) {
      int nl = wave * 16 + k;
      int n = (b << BIN_SH) + nl;
      if (n >= N_NODES) break;
      int e1 = sc[nl], e0 = e1 - h[nl];
      f32x4 a0 = {0.f, 0.f, 0.f, 0.f}, a1 = {0.f, 0.f, 0.f, 0.f};
      f32x4 a2 = {0.f, 0.f, 0.f, 0.f}, a3 = {0.f, 0.f, 0.f, 0.f};
      int i = e0;
      for (; i + 15 < e1; i += 16) {
        unsigned r0 = srt[i + g];
        unsigned r1 = srt[i + 4 + g];
        unsigned r2 = srt[i + 8 + g];
        unsigned r3 = srt[i + 12 + g];
        uint2 v0 = H1q[(r0 & 0x1FFFF) * (H_F / 4) + li];
        uint2 v1 = H1q[(r1 & 0x1FFFF) * (H_F / 4) + li];
        uint2 v2 = H1q[(r2 & 0x1FFFF) * (H_F / 4) + li];
        uint2 v3 = H1q[(r3 & 0x1FFFF) * (H_F / 4) + li];
        float w0 = (float)(r0 >> 17) * wsc, w1 = (float)(r1 >> 17) * wsc;
        float w2 = (float)(r2 >> 17) * wsc, w3 = (float)(r3 >> 17) * wsc;
        a0[0] += __uint_as_float(v0.x << 16) * w0;
        a0[1] += __uint_as_float(v0.x & 0xFFFF0000u) * w0;
        a0[2] += __uint_as_float(v0.y << 16) * w0;
        a0[3] += __uint_as_float(v0.y & 0xFFFF0000u) * w0;
        a1[0] += __uint_as_float(v1.x << 16) * w1;
        a1[1] += __uint_as_float(v1.x & 0xFFFF0000u) * w1;
        a1[2] += __uint_as_float(v1.y << 16) * w1;
        a1[3] += __uint_as_float(v1.y & 0xFFFF0000u) * w1;
        a2[0] += __uint_as_float(v2.x << 16) * w2;
        a2[1] += __uint_as_float(v2.x & 0xFFFF0000u) * w2;
        a2[2] += __uint_as_float(v2.y << 16) * w2;
        a2[3] += __uint_as_float(v2.y & 0xFFFF0000u) * w2;
        a3[0] += __uint_as_float(v3.x << 16) * w3;
        a3[1] += __uint_as_float(v3.x & 0xFFFF0000u) * w3;
        a3[2] += __uint_as_float(v3.y << 16) * w3;
        a3[3] += __uint_as_float(v3.y & 0xFFFF0000u) * w3;
      }
      for (; i + 3 < e1; i += 4) {
        unsigned r0 = srt[i + g];
        uint2 v0 = H1q[(r0 & 0x1FFFF) * (H_F / 4) + li];
        float w0 = (float)(r0 >> 17) * wsc;
        a0[0] += __uint_as_float(v0.x << 16) * w0;
        a0[1] += __uint_as_float(v0.x & 0xFFFF0000u) * w0;
        a0[2] += __uint_as_float(v0.y << 16) * w0;
        a0[3] += __uint_as_float(v0.y & 0xFFFF0000u) * w0;
      }
      if (i + g < e1) {
        unsigned r0 = srt[i + g];
        uint2 v0 = H1q[(r0 & 0x1FFFF) * (H_F / 4) + li];
        float w0 = (float)(r0 >> 17) * wsc;
        a1[0] += __uint_as_float(v0.x << 16) * w0;
        a1[1] += __uint_as_float(v0.x & 0xFFFF0000u) * w0;
        a1[2] += __uint_as_float(v0.y << 16) * w0;
        a1[3] += __uint_as_float(v0.y & 0xFFFF0000u) * w0;
      }
      f32x4 a = (a0 + a1) + (a2 + a3);
#pragma unroll
      for (int c = 0; c < 4; ++c) {
        a[c] += __shfl_xor(a[c], 16, 64);
        a[c] += __shfl_xor(a[c], 32, 64);
      }
      if (g == 0) {
        float r0 = fmaxf(a[0] + bb0, 0.f);
        float r1 = fmaxf(a[1] + bb1, 0.f);
        float r2 = fmaxf(a[2] + bb2, 0.f);
        float r3 = fmaxf(a[3] + bb3, 0.f);
        unsigned p0 = (unsigned)f2bf(r0) | ((unsigned)f2bf(r1) << 16);
        unsigned p1 = (unsigned)f2bf(r2) | ((unsigned)f2bf(r3) << 16);
        *(uint2*)&aggU[nl * AGG_STRIDE + li * 2] = make_uint2(p0, p1);
      }
    }
    __syncthreads();
    // ---- fused gemm2: wave wv handles nodes wv*16..wv*16+15 ----
    int l = lane & 15, q = lane >> 4;
    int nl0 = wave * 16;
    f32x4 acc = {0.f, 0.f, 0.f, 0.f};
#pragma unroll
    for (int s = 0; s < 2; ++s) {
      bf16x8 afr =
          *(const bf16x8*)&aggU[(nl0 + l) * AGG_STRIDE + s * 16 + q * 4];
      bf16x8 bfr = *(const bf16x8*)&ldsW2[s * 512 + lane * 8];
      acc = __builtin_amdgcn_mfma_f32_16x16x32_bf16(afr, bfr, acc, 0, 0, 0);
    }
    int node0 = (b << BIN_SH) + nl0;
#pragma unroll
    for (int r = 0; r < 4; ++r) {
      int n = node0 + q * 4 + r;
      if (n < N_NODES) H2b[(size_t)n * C_F + l] = f2bf(acc[r]);
    }
  }
  gridbar(&bar[2]);

  // ======================= Phase D =======================
  {
    const uint2* H2q = (const uint2*)H2b;
    int g = lane >> 2, li = lane & 3;
    const float wsc = 1.0f / 32767.0f;
    float bb0 = b2[li * 4], bb1 = b2[li * 4 + 1];
    float bb2 = b2[li * 4 + 2], bb3 = b2[li * 4 + 3];
    for (int k = 0; k < 16; ++k) {
      int nl = wave * 16 + k;
      int n = (b << BIN_SH) + nl;
      if (n >= N_NODES) break;
      int e1 = sc[nl], e0 = e1 - h[nl];
      f32x4 a0 = {0.f, 0.f, 0.f, 0.f};
      int i = e0;
      for (; i + 15 < e1; i += 16) {
        unsigned r0 = srt[i + g];
        uint2 v0 = H2q[(r0 & 0x1FFFF) * (C_F / 4) + li];
        float w0 = (float)(r0 >> 17) * wsc;
        a0[0] += __uint_as_float(v0.x << 16) * w0;
        a0[1] += __uint_as_float(v0.x & 0xFFFF0000u) * w0;
        a0[2] += __uint_as_float(v0.y << 16) * w0;
        a0[3] += __uint_as_float(v0.y & 0xFFFF0000u) * w0;
      }
      if (i + g < e1) {
        unsigned r0 = srt[i + g];
        uint2 v0 = H2q[(r0 & 0x1FFFF) * (C_F / 4) + li];
        float w0 = (float)(r0 >> 17) * wsc;
        a0[0] += __uint_as_float(v0.x << 16) * w0;
        a0[1] += __uint_as_float(v0.x & 0xFFFF0000u) * w0;
        a0[2] += __uint_as_float(v0.y << 16) * w0;
        a0[3] += __uint_as_float(v0.y & 0xFFFF0000u) * w0;
      }
#pragma unroll
      for (int c = 0; c < 4; ++c) {
        a0[c] += __shfl_xor(a0[c], 4, 64);
        a0[c] += __shfl_xor(a0[c], 8, 64);
        a0[c] += __shfl_xor(a0[c], 16, 64);
        a0[c] += __shfl_xor(a0[c], 32, 64);
      }
      if (g == 0) {
        float4 o;
        o.x = a0[0] + bb0;
        o.y = a0[1] + bb1;
        o.z = a0[2] + bb2;
        o.w = a0[3] + bb3;
        *(float4*)&out[(size_t)n * C_F + li * 4] = o;
      }
    }
  }
}

extern "C" void kernel_launch(void* const* d_in, const int* in_sizes, int n_in,
                              void* d_out, int out_size, void* d_ws,
                              size_t ws_size, hipStream_t stream) {
  const float* X  = (const float*)d_in[0];
  const float* ew = (const float*)d_in[1];
  const float* W1 = (const float*)d_in[2];
  const float* b1 = (const float*)d_in[3];
  const float* W2 = (const float*)d_in[4];
  const float* b2 = (const float*)d_in[5];
  const int* src  = (const int*)d_in[6];
  const int* dst  = (const int*)d_in[7];
  float* out = (float*)d_out;

  // Workspace (~33.6 MB):
  //   H1b bf16 [N x 64] 12.8 MB
  //   H2b bf16 [N x 16]  3.2 MB
  //   ebin int2 [NBINS x BCAP] 17.6 MB
  //   binCnt int [NBINS] + bar int [4]  (zeroed by the memset below)
  unsigned short* H1b = (unsigned short*)d_ws;
  unsigned short* H2b = H1b + (size_t)N_NODES * H_F;
  int2* ebin  = (int2*)(H2b + (size_t)N_NODES * C_F);
  int* binCnt = (int*)(ebin + (size_t)NBINS * BCAP);
  int* bar    = binCnt + NBINS;

  hipMemsetAsync(binCnt, 0, (NBINS + 4) * sizeof(int), stream);
  gcn_mega<<<NBINS, 512, 0, stream>>>(src, dst, ew, X, W1, b1, W2, b2, binCnt,
                                      ebin, H1b, H2b, out, bar);
}

// Round 8
// 202.349 us; speedup vs baseline: 5.7596x; 5.7596x over previous
//
#include <hip/hip_runtime.h>

#define N_NODES 100000
#define N_EDGES 1600000
#define IN_F 128
#define H_F 64
#define C_F 16

#define BIN_SH 7
#define BIN_NODES 128          // 1 << BIN_SH
#define NBINS 782              // ceil(100000 / 128)
#define BCAP 2816              // fixed bin capacity (mean 2048, sigma 45 -> +17s)
#define PART_BLOCKS 196        // ceil(400000 int4 / 2048 per block) - 8192 edges/blk
#define GEMM1_BLOCKS 1563      // ceil(6250 row-tiles / 4 waves)
#define RMAX 6                 // ceil(BCAP / 512) records/thread in sort cache
#define AGG_STRIDE 36          // LDS agg tile row stride in words (144 B)

typedef __attribute__((ext_vector_type(8))) short bf16x8;  // 8 bf16 (4 VGPRs)
typedef __attribute__((ext_vector_type(4))) float f32x4;   // MFMA C/D

// fp32 -> bf16 round-to-nearest-even (finite inputs)
__device__ inline unsigned short f2bf(float f) {
  unsigned u = __float_as_uint(f);
  unsigned r = (u + 0x7fff + ((u >> 16) & 1)) >> 16;
  return (unsigned short)r;
}

// ---------------- fused partition + GEMM1 (independent work) --------------
// Blocks [0, PART_BLOCKS): partition edges into 782 fixed-capacity dst-range
// bins. 8192 edges/block (32/thread): halves block-bin pair count vs R2's
// 4096 -> per-bin write runs ~84 B span full 64 B lines -> less partial-line
// writeback across XCDs (R4 measured the inverse: 1024-edge blocks doubled
// WRITE_SIZE). Blocks [PART_BLOCKS..): MFMA GEMM1 H1b = bf16(X @ W1).
__global__ __launch_bounds__(256) void part_gemm1_kernel(
    const int* __restrict__ src, const int* __restrict__ dst,
    const float* __restrict__ ew, int* __restrict__ binCnt,
    int2* __restrict__ ebin, const float* __restrict__ X,
    const float* __restrict__ W1, unsigned short* __restrict__ H1b) {
  __shared__ char ldsraw[16 * 1024];
  int tid = threadIdx.x;
  if (blockIdx.x < PART_BLOCKS) {
    // ---- partition path ----
    int* hist = (int*)ldsraw;   // NBINS ints
    int* base = hist + NBINS;   // NBINS ints (reserve base, then cursor)
    for (int i = tid; i < NBINS; i += 256) hist[i] = 0;
    __syncthreads();
    int i0 = blockIdx.x * 2048;  // int4 index base (8192 edges/block)
    int iHi = i0 + 2048;
    if (iHi > N_EDGES / 4) iHi = N_EDGES / 4;
    const int4* d4p = (const int4*)dst;
    const int4* s4p = (const int4*)src;
    const float4* w4p = (const float4*)ew;
    unsigned key[32];
    unsigned aux[32];
#pragma unroll
    for (int it = 0; it < 8; ++it) {
      int i = i0 + it * 256 + tid;
      if (i < iHi) {
        int4 d = d4p[i];
        int4 s = s4p[i];
        float4 w = w4p[i];
#pragma unroll
        for (int j = 0; j < 4; ++j) {
          int dd = (&d.x)[j];
          int ss = (&s.x)[j];
          float ww = (&w.x)[j];
          int bb = dd >> BIN_SH;
          unsigned wf = (unsigned)(ww * 32767.0f + 0.5f);
          key[it * 4 + j] =
              (unsigned)ss | ((unsigned)(dd & (BIN_NODES - 1)) << 17);
          aux[it * 4 + j] = wf | ((unsigned)bb << 15);
          atomicAdd(&hist[bb], 1);
        }
      }
    }
    __syncthreads();
    for (int i = tid; i < NBINS; i += 256)
      base[i] = hist[i] ? atomicAdd(&binCnt[i], hist[i]) : 0;
    __syncthreads();
#pragma unroll
    for (int it = 0; it < 8; ++it) {
      int i = i0 + it * 256 + tid;
      if (i < iHi) {
        int pos[4];
#pragma unroll
        for (int j = 0; j < 4; ++j)
          pos[j] = atomicAdd(&base[aux[it * 4 + j] >> 15], 1);
#pragma unroll
        for (int j = 0; j < 4; ++j) {
          unsigned a = aux[it * 4 + j];
          ebin[(size_t)(a >> 15) * BCAP + pos[j]] =
              make_int2((int)key[it * 4 + j], (int)(a & 0x7FFF));
        }
      }
    }
  } else {
    // ---- gemm1 path ----
    short* ldsB = (short*)ldsraw;  // 16 frags x 512 bf16 = 16 KB
    for (int idx = tid; idx < 16 * 512; idx += 256) {
      int frag = idx >> 9;    // c*4 + s
      int entry = idx & 511;  // lane*8 + j
      int lane = entry >> 3, j = entry & 7;
      int c = frag >> 2, s = frag & 3;
      int k = s * 32 + (lane >> 4) * 8 + j;
      int n = c * 16 + (lane & 15);
      ldsB[idx] = (short)f2bf(W1[k * H_F + n]);
    }
    __syncthreads();
    int wave = tid >> 6;
    int lane = tid & 63;
    int rt = (blockIdx.x - PART_BLOCKS) * 4 + wave;  // 16-node row tile
    if (rt >= N_NODES / 16) return;                  // 6250 tiles exactly
    int node0 = rt * 16;
    int l = lane & 15, q = lane >> 4;
    const float* xp = X + (size_t)(node0 + l) * IN_F + q * 8;
    f32x4 acc[4] = {f32x4{0.f, 0.f, 0.f, 0.f}, f32x4{0.f, 0.f, 0.f, 0.f},
                    f32x4{0.f, 0.f, 0.f, 0.f}, f32x4{0.f, 0.f, 0.f, 0.f}};
#pragma unroll
    for (int s = 0; s < 4; ++s) {
      float4 x0 = *(const float4*)(xp + s * 32);
      float4 x1 = *(const float4*)(xp + s * 32 + 4);
      bf16x8 a;
      a[0] = f2bf(x0.x); a[1] = f2bf(x0.y); a[2] = f2bf(x0.z); a[3] = f2bf(x0.w);
      a[4] = f2bf(x1.x); a[5] = f2bf(x1.y); a[6] = f2bf(x1.z); a[7] = f2bf(x1.w);
#pragma unroll
      for (int c = 0; c < 4; ++c) {
        bf16x8 b = *(const bf16x8*)&ldsB[(c * 4 + s) * 512 + lane * 8];
        acc[c] = __builtin_amdgcn_mfma_f32_16x16x32_bf16(a, b, acc[c], 0, 0, 0);
      }
    }
    // C/D: col = lane&15 (feat), row = q*4 + reg (node)
#pragma unroll
    for (int c = 0; c < 4; ++c)
#pragma unroll
      for (int r = 0; r < 4; ++r)
        H1b[(size_t)(node0 + q * 4 + r) * H_F + c * 16 + l] = f2bf(acc[c][r]);
  }
}

// ---------------- gather1f: per-bin sort + gather + FUSED gemm2 -----------
// Block = bin (128 nodes), 512 threads.  (R2-proven structure, 48.4 us.)
// Phase 1: counting-sort bin edges in LDS; persist sorted 4 B keys (in
//          place, coalesced) + per-node segments for gather2s.
// Phase 2: 8 waves x 16 nodes; 4 edge-groups x 16 lanes, uint2 per lane,
//          16 H1b rows in flight; shfl_xor(16,32) combine; epilogue packs
//          bf16(relu(sum + b1)) into the LDS agg tile (stride 144 B).
// Phase 3: fused GEMM2 — per wave one 16x16 MFMA pair (K=64); writes H2b.
__global__ __launch_bounds__(512) void gather1f_kernel(
    const uint2* __restrict__ H1q, const int* __restrict__ binCnt,
    int2* __restrict__ ebin, int2* __restrict__ segB,
    const float* __restrict__ b1, const float* __restrict__ W2,
    unsigned short* __restrict__ H2b) {
  __shared__ int h[BIN_NODES], sc[BIN_NODES], cur[BIN_NODES];
  __shared__ unsigned srt[BCAP];
  __shared__ unsigned aggU[BIN_NODES * AGG_STRIDE];  // bf16-pair packed
  __shared__ short ldsW2[2 * 512];
  int b = blockIdx.x, tid = threadIdx.x;
  // W2 swizzle fill (overlaps sort; before first barrier)
  for (int idx = tid; idx < 1024; idx += 512) {
    int sfrag = idx >> 9;
    int entry = idx & 511;
    int lane = entry >> 3, j = entry & 7;
    int k = sfrag * 32 + (lane >> 4) * 8 + j;
    int c = lane & 15;
    ldsW2[idx] = (short)f2bf(W2[k * C_F + c]);
  }
  int lo = b * BCAP;
  int cnt = binCnt[b];
  if (tid < BIN_NODES) h[tid] = 0;
  __syncthreads();
  unsigned rk[RMAX];
  int rd[RMAX];
  int rn = 0;
#pragma unroll
  for (int j = 0; j < RMAX; ++j) {
    int e = j * 512 + tid;
    if (e < cnt) {
      int2 r = ebin[lo + e];
      int dl = (((unsigned)r.x) >> 17) & (BIN_NODES - 1);
      rk[j] = ((unsigned)r.x & 0x1FFFF) | ((unsigned)r.y << 17);
      rd[j] = dl;
      atomicAdd(&h[dl], 1);
      rn = j + 1;
    }
  }
  __syncthreads();
  if (tid < BIN_NODES) sc[tid] = h[tid];
  __syncthreads();
#pragma unroll
  for (int d = 1; d < BIN_NODES; d <<= 1) {
    int t = 0;
    if (tid < BIN_NODES && tid >= d) t = sc[tid - d];
    __syncthreads();
    if (tid < BIN_NODES) sc[tid] += t;
    __syncthreads();
  }
  if (tid < BIN_NODES) cur[tid] = sc[tid] - h[tid];
  __syncthreads();
#pragma unroll
  for (int j = 0; j < RMAX; ++j)
    if (j < rn) {
      int pos = atomicAdd(&cur[rd[j]], 1);
      srt[pos] = rk[j];
    }
  __syncthreads();
  // ---- persist sorted keys + per-node bin-local segments for gather2s ----
  {
    unsigned* ebinU = (unsigned*)ebin;
    int lo2 = lo << 1;  // 4 B-unit base of this bin's 8 B region
    for (int i = tid; i < cnt; i += 512) ebinU[lo2 + i] = srt[i];
    if (tid < BIN_NODES) {
      int n = (b << BIN_SH) + tid;
      if (n < N_NODES) segB[n] = make_int2(sc[tid] - h[tid], sc[tid]);
    }
  }
  // ---- gather phase ----
  int wv = tid >> 6, lane = tid & 63, g = lane >> 4, li = lane & 15;
  const float wsc = 1.0f / 32767.0f;
  float bb0 = b1[li * 4], bb1 = b1[li * 4 + 1];
  float bb2 = b1[li * 4 + 2], bb3 = b1[li * 4 + 3];
  for (int k = 0; k < 16; ++k) {
    int nl = wv * 16 + k;
    int n = (b << BIN_SH) + nl;
    if (n >= N_NODES) break;
    int e1 = sc[nl], e0 = e1 - h[nl];
    f32x4 a0 = {0.f, 0.f, 0.f, 0.f}, a1 = {0.f, 0.f, 0.f, 0.f};
    f32x4 a2 = {0.f, 0.f, 0.f, 0.f}, a3 = {0.f, 0.f, 0.f, 0.f};
    int i = e0;
    for (; i + 15 < e1; i += 16) {
      unsigned r0 = srt[i + g];
      unsigned r1 = srt[i + 4 + g];
      unsigned r2 = srt[i + 8 + g];
      unsigned r3 = srt[i + 12 + g];
      uint2 v0 = H1q[(r0 & 0x1FFFF) * (H_F / 4) + li];
      uint2 v1 = H1q[(r1 & 0x1FFFF) * (H_F / 4) + li];
      uint2 v2 = H1q[(r2 & 0x1FFFF) * (H_F / 4) + li];
      uint2 v3 = H1q[(r3 & 0x1FFFF) * (H_F / 4) + li];
      float w0 = (float)(r0 >> 17) * wsc, w1 = (float)(r1 >> 17) * wsc;
      float w2 = (float)(r2 >> 17) * wsc, w3 = (float)(r3 >> 17) * wsc;
      a0[0] += __uint_as_float(v0.x << 16) * w0;
      a0[1] += __uint_as_float(v0.x & 0xFFFF0000u) * w0;
      a0[2] += __uint_as_float(v0.y << 16) * w0;
      a0[3] += __uint_as_float(v0.y & 0xFFFF0000u) * w0;
      a1[0] += __uint_as_float(v1.x << 16) * w1;
      a1[1] += __uint_as_float(v1.x & 0xFFFF0000u) * w1;
      a1[2] += __uint_as_float(v1.y << 16) * w1;
      a1[3] += __uint_as_float(v1.y & 0xFFFF0000u) * w1;
      a2[0] += __uint_as_float(v2.x << 16) * w2;
      a2[1] += __uint_as_float(v2.x & 0xFFFF0000u) * w2;
      a2[2] += __uint_as_float(v2.y << 16) * w2;
      a2[3] += __uint_as_float(v2.y & 0xFFFF0000u) * w2;
      a3[0] += __uint_as_float(v3.x << 16) * w3;
      a3[1] += __uint_as_float(v3.x & 0xFFFF0000u) * w3;
      a3[2] += __uint_as_float(v3.y << 16) * w3;
      a3[3] += __uint_as_float(v3.y & 0xFFFF0000u) * w3;
    }
    for (; i + 3 < e1; i += 4) {
      unsigned r0 = srt[i + g];
      uint2 v0 = H1q[(r0 & 0x1FFFF) * (H_F / 4) + li];
      float w0 = (float)(r0 >> 17) * wsc;
      a0[0] += __uint_as_float(v0.x << 16) * w0;
      a0[1] += __uint_as_float(v0.x & 0xFFFF0000u) * w0;
      a0[2] += __uint_as_float(v0.y << 16) * w0;
      a0[3] += __uint_as_float(v0.y & 0xFFFF0000u) * w0;
    }
    if (i + g < e1) {
      unsigned r0 = srt[i + g];
      uint2 v0 = H1q[(r0 & 0x1FFFF) * (H_F / 4) + li];
      float w0 = (float)(r0 >> 17) * wsc;
      a1[0] += __uint_as_float(v0.x << 16) * w0;
      a1[1] += __uint_as_float(v0.x & 0xFFFF0000u) * w0;
      a1[2] += __uint_as_float(v0.y << 16) * w0;
      a1[3] += __uint_as_float(v0.y & 0xFFFF0000u) * w0;
    }
    f32x4 a = (a0 + a1) + (a2 + a3);
#pragma unroll
    for (int c = 0; c < 4; ++c) {
      a[c] += __shfl_xor(a[c], 16, 64);
      a[c] += __shfl_xor(a[c], 32, 64);
    }
    if (g == 0) {
      // bias + relu + bf16 pack straight into the agg tile (feats 4li..4li+3)
      float r0 = fmaxf(a[0] + bb0, 0.f);
      float r1 = fmaxf(a[1] + bb1, 0.f);
      float r2 = fmaxf(a[2] + bb2, 0.f);
      float r3 = fmaxf(a[3] + bb3, 0.f);
      unsigned p0 = (unsigned)f2bf(r0) | ((unsigned)f2bf(r1) << 16);
      unsigned p1 = (unsigned)f2bf(r2) | ((unsigned)f2bf(r3) << 16);
      *(uint2*)&aggU[nl * AGG_STRIDE + li * 2] = make_uint2(p0, p1);
    }
  }
  __syncthreads();
  // ---- fused gemm2: wave wv handles nodes wv*16..wv*16+15 ----
  int l = lane & 15, q = lane >> 4;
  int nl0 = wv * 16;
  f32x4 acc = {0.f, 0.f, 0.f, 0.f};
#pragma unroll
  for (int s = 0; s < 2; ++s) {
    bf16x8 afr = *(const bf16x8*)&aggU[(nl0 + l) * AGG_STRIDE + s * 16 + q * 4];
    bf16x8 bfr = *(const bf16x8*)&ldsW2[s * 512 + lane * 8];
    acc = __builtin_amdgcn_mfma_f32_16x16x32_bf16(afr, bfr, acc, 0, 0, 0);
  }
  int node0 = (b << BIN_SH) + nl0;
#pragma unroll
  for (int r = 0; r < 4; ++r) {
    int n = node0 + q * 4 + r;
    if (n < N_NODES) H2b[(size_t)n * C_F + l] = f2bf(acc[r]);
  }
}

// ---------------- gather2s: NO sort — reuse gather1f's sorted keys --------
// (R2-proven structure.) Copy the bin's contiguous pre-sorted key span to
// LDS + per-node segments; gather: 16 edge-groups x 4 lanes, uint2 per
// lane, 16 edges in flight; shfl_xor(4..32) combine; 4 lanes write float4.
__global__ __launch_bounds__(512) void gather2s_kernel(
    const uint2* __restrict__ H2q, const int* __restrict__ binCnt,
    const int2* __restrict__ ebin, const int2* __restrict__ segB,
    const float* __restrict__ b2, float* __restrict__ out) {
  __shared__ int2 segl[BIN_NODES];
  __shared__ unsigned srt[BCAP];
  int b = blockIdx.x, tid = threadIdx.x;
  int cnt = binCnt[b];
  const unsigned* ebinU = (const unsigned*)ebin;
  int lo2 = (b * BCAP) << 1;
  for (int i = tid; i < cnt; i += 512) srt[i] = ebinU[lo2 + i];
  if (tid < BIN_NODES) {
    int n = (b << BIN_SH) + tid;
    segl[tid] = (n < N_NODES) ? segB[n] : make_int2(0, 0);
  }
  __syncthreads();
  // gather phase
  int wv = tid >> 6, lane = tid & 63, g = lane >> 2, li = lane & 3;
  const float wsc = 1.0f / 32767.0f;
  float bb0 = b2[li * 4], bb1 = b2[li * 4 + 1];
  float bb2 = b2[li * 4 + 2], bb3 = b2[li * 4 + 3];
  for (int k = 0; k < 16; ++k) {
    int nl = wv * 16 + k;
    int n = (b << BIN_SH) + nl;
    if (n >= N_NODES) break;
    int2 sgl = segl[nl];
    int e0 = sgl.x, e1 = sgl.y;
    f32x4 a0 = {0.f, 0.f, 0.f, 0.f};
    int i = e0;
    for (; i + 15 < e1; i += 16) {
      unsigned r0 = srt[i + g];
      uint2 v0 = H2q[(r0 & 0x1FFFF) * (C_F / 4) + li];
      float w0 = (float)(r0 >> 17) * wsc;
      a0[0] += __uint_as_float(v0.x << 16) * w0;
      a0[1] += __uint_as_float(v0.x & 0xFFFF0000u) * w0;
      a0[2] += __uint_as_float(v0.y << 16) * w0;
      a0[3] += __uint_as_float(v0.y & 0xFFFF0000u) * w0;
    }
    if (i + g < e1) {
      unsigned r0 = srt[i + g];
      uint2 v0 = H2q[(r0 & 0x1FFFF) * (C_F / 4) + li];
      float w0 = (float)(r0 >> 17) * wsc;
      a0[0] += __uint_as_float(v0.x << 16) * w0;
      a0[1] += __uint_as_float(v0.x & 0xFFFF0000u) * w0;
      a0[2] += __uint_as_float(v0.y << 16) * w0;
      a0[3] += __uint_as_float(v0.y & 0xFFFF0000u) * w0;
    }
#pragma unroll
    for (int c = 0; c < 4; ++c) {
      a0[c] += __shfl_xor(a0[c], 4, 64);
      a0[c] += __shfl_xor(a0[c], 8, 64);
      a0[c] += __shfl_xor(a0[c], 16, 64);
      a0[c] += __shfl_xor(a0[c], 32, 64);
    }
    if (g == 0) {
      float4 o;
      o.x = a0[0] + bb0;
      o.y = a0[1] + bb1;
      o.z = a0[2] + bb2;
      o.w = a0[3] + bb3;
      *(float4*)&out[(size_t)n * C_F + li * 4] = o;
    }
  }
}

extern "C" void kernel_launch(void* const* d_in, const int* in_sizes, int n_in,
                              void* d_out, int out_size, void* d_ws,
                              size_t ws_size, hipStream_t stream) {
  const float* X  = (const float*)d_in[0];
  const float* ew = (const float*)d_in[1];
  const float* W1 = (const float*)d_in[2];
  const float* b1 = (const float*)d_in[3];
  const float* W2 = (const float*)d_in[4];
  const float* b2 = (const float*)d_in[5];
  const int* src  = (const int*)d_in[6];
  const int* dst  = (const int*)d_in[7];
  float* out = (float*)d_out;

  // Workspace (~34.4 MB):
  //   H1b bf16 [N x 64] 12.8 MB
  //   H2b bf16 [N x 16]  3.2 MB (separate: live while H1b is read)
  //   ebin int2 [NBINS x BCAP] 17.6 MB (bins; reused for sorted 4 B keys)
  //   binCnt int [NBINS]
  //   segB int2 [N] 0.8 MB (per-node bin-local {e0,e1}, written by gather1f)
  unsigned short* H1b = (unsigned short*)d_ws;
  unsigned short* H2b = H1b + (size_t)N_NODES * H_F;
  int2* ebin  = (int2*)(H2b + (size_t)N_NODES * C_F);
  int* binCnt = (int*)(ebin + (size_t)NBINS * BCAP);
  int2* segB  = (int2*)(binCnt + NBINS);

  hipMemsetAsync(binCnt, 0, NBINS * sizeof(int), stream);
  part_gemm1_kernel<<<PART_BLOCKS + GEMM1_BLOCKS, 256, 0, stream>>>(
      src, dst, ew, binCnt, ebin, X, W1, H1b);
  gather1f_kernel<<<NBINS, 512, 0, stream>>>((const uint2*)H1b, binCnt, ebin,
                                             segB, b1, W2, H2b);
  gather2s_kernel<<<NBINS, 512, 0, stream>>>((const uint2*)H2b, binCnt, ebin,
                                             segB, b2, out);
}